// Round 5
// baseline (544.737 us; speedup 1.0000x reference)
//
#include <hip/hip_runtime.h>
#include <stdint.h>

// ---------------------------------------------------------------------------
// Problem constants: B=4, S=2048, D=2048, H=16, KVH=8, HD=128, N_REP=2
// ---------------------------------------------------------------------------
#define SEQ   2048
#define DIM   2048
#define NH    16
#define NKVH  8
#define HDIM  128
#define MTOT  8192      // B*S
#define LOG2E 1.44269504088896340736f

typedef short bf16x8 __attribute__((ext_vector_type(8)));   // 8 bf16 = 4 VGPRs
typedef float f32x4  __attribute__((ext_vector_type(4)));
typedef unsigned short us4 __attribute__((ext_vector_type(4)));

#define MFMA(a, b, c) __builtin_amdgcn_mfma_f32_16x16x32_bf16((a), (b), (c), 0, 0, 0)

__device__ inline unsigned short f2bf(float f) {
    unsigned u = __builtin_bit_cast(unsigned, f);
    u = (u + 0x7FFFu + ((u >> 16) & 1u)) >> 16;   // RNE
    return (unsigned short)u;
}

__device__ inline void stage16(const void* g, void* l) {
    __builtin_amdgcn_global_load_lds(
        (const __attribute__((address_space(1))) void*)g,
        (__attribute__((address_space(3))) void*)l,
        16, 0, 0);
}

// ---------------------------------------------------------------------------
// Prep: x f32 -> bf16
// ---------------------------------------------------------------------------
__global__ void conv_x(const float* __restrict__ x, unsigned short* __restrict__ xb) {
    long i = ((long)blockIdx.x * 256 + threadIdx.x) * 4;
    float4 v = *(const float4*)(x + i);
    us4 o = { f2bf(v.x), f2bf(v.y), f2bf(v.z), f2bf(v.w) };
    *(us4*)(xb + i) = o;
}

// ---------------------------------------------------------------------------
// Prep: weight (K=2048 rows x N cols, f32) -> transposed bf16 [N][2048]
// ---------------------------------------------------------------------------
__global__ void transpose_w(const float* __restrict__ in, unsigned short* __restrict__ out,
                            int N, int row_off) {
    __shared__ float t[32][33];
    int tx = threadIdx.x, ty = threadIdx.y;
    int n0 = blockIdx.x * 32, k0 = blockIdx.y * 32;
    for (int i = 0; i < 4; i++)
        t[ty + i * 8][tx] = in[(long)(k0 + ty + i * 8) * N + n0 + tx];
    __syncthreads();
    for (int i = 0; i < 4; i++)
        out[(long)(row_off + n0 + ty + i * 8) * 2048 + k0 + tx] = f2bf(t[tx][ty + i * 8]);
}

// ---------------------------------------------------------------------------
// Prep: V (b,kvh,s,hd) bf16 -> V^T (b,kvh,hd,s) bf16
// ---------------------------------------------------------------------------
__global__ void transpose_v(const unsigned short* __restrict__ v, unsigned short* __restrict__ vt) {
    __shared__ unsigned short t[32][33];
    int tx = threadIdx.x, ty = threadIdx.y;
    int d0 = blockIdx.x * 32, s0 = blockIdx.y * 32, bk = blockIdx.z;
    const unsigned short* vin = v + (long)bk * SEQ * HDIM;
    unsigned short* vo = vt + (long)bk * HDIM * SEQ;
    for (int i = 0; i < 4; i++)
        t[ty + i * 8][tx] = vin[(long)(s0 + ty + i * 8) * HDIM + d0 + tx];
    __syncthreads();
    for (int i = 0; i < 4; i++)
        vo[(long)(d0 + ty + i * 8) * SEQ + s0 + tx] = t[tx][ty + i * 8];
}

// ---------------------------------------------------------------------------
// QKV GEMM (reverted to the empirically-best round-0 v3): BK=64, 128x128
// tile, 256 threads, single-buffer 2-sync schedule, ~3-4 blocks/CU of
// implicit cross-block overlap (measured 155 us / 42% MfmaUtil — beats both
// deep-pipeline attempts at 1 block/CU: 170/163 us, 35-36%).
// XOR-swizzled LDS, C^T MFMA orientation, in-lane RoPE epilogue.
// ---------------------------------------------------------------------------
__launch_bounds__(256, 2)
__global__ void qkv_gemm(const unsigned short* __restrict__ xb,
                         const unsigned short* __restrict__ wt,
                         const float* __restrict__ pcos, const float* __restrict__ psin,
                         unsigned short* __restrict__ qb, unsigned short* __restrict__ kbuf,
                         unsigned short* __restrict__ vbuf) {
    constexpr int K = DIM;
    __shared__ __align__(16) unsigned short As[128 * 64];
    __shared__ __align__(16) unsigned short Bs[128 * 64];
    const int tid = threadIdx.x;
    const int m0 = blockIdx.y * 128;
    const int n0 = blockIdx.x * 128;
    const int w = tid >> 6, lane = tid & 63, qq = lane >> 4, ln = lane & 15;
    const int wm = w >> 1, wn = w & 1;

    f32x4 acc[4][4] = {};

    const int arow = tid >> 3;                          // 0..31 (row within 32-row round)
    const int aswz = ((tid & 7) ^ (arow & 7)) * 8;      // swizzled source col (shorts)
    const unsigned short* ag = xb + (long)(m0 + arow) * K + aswz;
    const unsigned short* bg = wt + (long)(n0 + arow) * K + aswz;
    unsigned short* al = As + tid * 8;
    unsigned short* bl = Bs + tid * 8;

    for (int kk = 0; kk < K; kk += 64) {
        __syncthreads();
        stage16(ag + kk,          al);
        stage16(ag + kk + 32 * K, al + 2048);
        stage16(ag + kk + 64 * K, al + 4096);
        stage16(ag + kk + 96 * K, al + 6144);
        stage16(bg + kk,          bl);
        stage16(bg + kk + 32 * K, bl + 2048);
        stage16(bg + kk + 64 * K, bl + 4096);
        stage16(bg + kk + 96 * K, bl + 6144);
        __syncthreads();
        bf16x8 a[2][4], b[2][4];
        for (int ks = 0; ks < 2; ks++) {
            for (int mt = 0; mt < 4; mt++)
                a[ks][mt] = *(const bf16x8*)&As[(wm * 64 + mt * 16 + ln) * 64 + (((ks * 4 + qq) ^ (ln & 7)) * 8)];
            for (int nt = 0; nt < 4; nt++)
                b[ks][nt] = *(const bf16x8*)&Bs[(wn * 64 + nt * 16 + ln) * 64 + (((ks * 4 + qq) ^ (ln & 7)) * 8)];
        }
        for (int ks = 0; ks < 2; ks++)
            for (int mt = 0; mt < 4; mt++)
                for (int nt = 0; nt < 4; nt++)
                    acc[mt][nt] = MFMA(b[ks][nt], a[ks][mt], acc[mt][nt]);   // C^T
    }

    // epilogue: n = n0 + wn*64 + nt*16 + qq*4 + r (regs), m = m0 + wm*64 + mt*16 + ln
    const bool isv = (n0 >= 3072);          // block-uniform: no RoPE for v
    for (int mt = 0; mt < 4; mt++) {
        int m = m0 + wm * 64 + mt * 16 + ln;
        int b_ = m >> 11, s = m & (SEQ - 1);
        const float* crow = pcos + s * 64;
        const float* srow = psin + s * 64;
        for (int nt = 0; nt < 4; nt++) {
            int n = n0 + wn * 64 + nt * 16 + qq * 4;
            int d = n & (HDIM - 1);
            f32x4 v = acc[mt][nt];
            float o0, o1, o2, o3;
            if (!isv) {                      // RoPE, pairs in-lane
                int i = d >> 1;
                float2 cc = *(const float2*)(crow + i);
                float2 ss = *(const float2*)(srow + i);
                o0 = v[0] * cc.x - v[1] * ss.x;
                o1 = v[0] * ss.x + v[1] * cc.x;
                o2 = v[2] * cc.y - v[3] * ss.y;
                o3 = v[2] * ss.y + v[3] * cc.y;
            } else {
                o0 = v[0]; o1 = v[1]; o2 = v[2]; o3 = v[3];
            }
            us4 pu = { f2bf(o0), f2bf(o1), f2bf(o2), f2bf(o3) };
            if (n < 2048) {
                int hh = n >> 7;
                *(us4*)&qb[((long)(b_ * NH + hh) * SEQ + s) * HDIM + d] = pu;
            } else if (n < 3072) {
                int kvh = (n - 2048) >> 7;
                *(us4*)&kbuf[((long)(b_ * NKVH + kvh) * SEQ + s) * HDIM + d] = pu;
            } else {
                int kvh = (n - 3072) >> 7;
                *(us4*)&vbuf[((long)(b_ * NKVH + kvh) * SEQ + s) * HDIM + d] = pu;
            }
        }
    }
}

// ---------------------------------------------------------------------------
// Flash attention v3c: v3b + s_setprio(1/0) around both MFMA clusters
// (T5: +4-7% measured on attention; 2 independent blocks/CU give the CU
// scheduler waves at different phases to arbitrate).
// ---------------------------------------------------------------------------
__launch_bounds__(256, 2)
__global__ void flash(const unsigned short* __restrict__ qb,
                      const unsigned short* __restrict__ kb,
                      const unsigned short* __restrict__ vtb,
                      unsigned short* __restrict__ aout) {
    __shared__ __align__(16) unsigned short KV[32768];   // K: shorts [0,16384)  V^T: [16384,32768)
    const int tid = threadIdx.x;
    const int w = tid >> 6, lane = tid & 63, qq = lane >> 4, ln = lane & 15;
    unsigned short* Pseg = KV + w * 4096;                // P overlay, wave-private 8 KB

    // block swizzle: XCD = flat%8; pin 4 (b,kv) pairs per XCD
    int f = blockIdx.x + (blockIdx.y << 3) + (blockIdx.z << 7);  // grid (8,16,4)
    int xcd = f & 7, j = f >> 3;
    int bkv = xcd + 8 * (j & 3);
    int b = bkv >> 3, kv = bkv & 7;
    int rem = j >> 2;
    int h = kv * 2 + (rem & 1);
    int qpair = rem >> 1;

    const unsigned short* qbase = qb + (long)(b * NH + h) * SEQ * HDIM;
    const unsigned short* kbase = kb + (long)(b * NKVH + kv) * SEQ * HDIM;
    const unsigned short* vbase = vtb + (long)(b * NKVH + kv) * HDIM * SEQ;
    const float SCL2 = 0.088388347648318447f * LOG2E;   // scale * log2(e), folded

    const int srow = tid >> 4;                 // staging: row within 16-row group
    const int sswz = (tid & 15) ^ srow;        // staging: swizzled source unit

    for (int phase = 0; phase < 2; phase++) {
        const int qt = (phase == 0) ? qpair : 15 - qpair;
        const int q0 = qt * 128 + w * 32;

        // Q fragments (B-operand layout: lane=q, k-contiguous)
        bf16x8 qf[2][4];
        for (int nt = 0; nt < 2; nt++)
            for (int ks = 0; ks < 4; ks++)
                qf[nt][ks] = *(const bf16x8*)&qbase[(long)(q0 + nt * 16 + ln) * HDIM + ks * 32 + qq * 8];

        float m[2] = { -3e38f, -3e38f }, l[2] = { 0.f, 0.f };
        f32x4 oacc[8][2] = {};

        #pragma unroll 1
        for (int kt = 0; kt <= qt; kt++) {
            const int k0 = kt * 128;

            __syncthreads();   // B_pre: everyone done reading previous K/V/P
            // stage K [key][hd-unit^swz] and V^T [hd][key-unit^swz]
            char* kl = (char*)KV;
            #pragma unroll
            for (int r = 0; r < 8; r++) {
                int key = r * 16 + srow;
                stage16(kbase + (long)(k0 + key) * HDIM + sswz * 8, kl + r * 4096 + tid * 16);
            }
            #pragma unroll
            for (int r = 0; r < 8; r++) {
                int hd = r * 16 + srow;
                stage16(vbase + (long)hd * SEQ + k0 + sswz * 8, kl + 32768 + r * 4096 + tid * 16);
            }
            __syncthreads();   // B_vis: compiler's vmcnt(0) drain + visibility

            // ---- S^T = K Q^T : A-frags from swizzled LDS ----
            f32x4 sacc[8][2] = {};
            __builtin_amdgcn_s_setprio(1);
            #pragma unroll
            for (int mt = 0; mt < 8; mt++) {
                const unsigned short* kr = &KV[(mt * 16 + ln) * 128];
                bf16x8 kf0 = *(const bf16x8*)&kr[((0 + qq) ^ ln) * 8];
                bf16x8 kf1 = *(const bf16x8*)&kr[((4 + qq) ^ ln) * 8];
                bf16x8 kf2 = *(const bf16x8*)&kr[((8 + qq) ^ ln) * 8];
                bf16x8 kf3 = *(const bf16x8*)&kr[((12 + qq) ^ ln) * 8];
                sacc[mt][0] = MFMA(kf0, qf[0][0], sacc[mt][0]);
                sacc[mt][1] = MFMA(kf0, qf[1][0], sacc[mt][1]);
                sacc[mt][0] = MFMA(kf1, qf[0][1], sacc[mt][0]);
                sacc[mt][1] = MFMA(kf1, qf[1][1], sacc[mt][1]);
                sacc[mt][0] = MFMA(kf2, qf[0][2], sacc[mt][0]);
                sacc[mt][1] = MFMA(kf2, qf[1][2], sacc[mt][1]);
                sacc[mt][0] = MFMA(kf3, qf[0][3], sacc[mt][0]);
                sacc[mt][1] = MFMA(kf3, qf[1][3], sacc[mt][1]);
            }
            __builtin_amdgcn_s_setprio(0);

            __syncthreads();   // B_k: all waves done reading K region (P overlays it)

            // ---- online softmax in raw units (scale folded into SCL2) ----
            const bool diag = (kt == qt);
            #pragma unroll
            for (int nt = 0; nt < 2; nt++) {
                const int q = q0 + nt * 16 + ln;
                float mx = m[nt];
                #pragma unroll
                for (int mt = 0; mt < 8; mt++)
                    #pragma unroll
                    for (int r = 0; r < 4; r++) {
                        float v = sacc[mt][nt][r];
                        if (diag && (k0 + mt * 16 + qq * 4 + r > q)) v = -3e38f;
                        sacc[mt][nt][r] = v;
                        mx = fmaxf(mx, v);
                    }
                mx = fmaxf(mx, __shfl_xor(mx, 16));
                mx = fmaxf(mx, __shfl_xor(mx, 32));
                float alpha = exp2f((m[nt] - mx) * SCL2);
                m[nt] = mx;
                float rs = 0.f;
                #pragma unroll
                for (int mt = 0; mt < 8; mt++) {
                    float p0 = exp2f((sacc[mt][nt][0] - mx) * SCL2);
                    float p1 = exp2f((sacc[mt][nt][1] - mx) * SCL2);
                    float p2 = exp2f((sacc[mt][nt][2] - mx) * SCL2);
                    float p3 = exp2f((sacc[mt][nt][3] - mx) * SCL2);
                    rs += (p0 + p1) + (p2 + p3);
                    us4 pu = { f2bf(p0), f2bf(p1), f2bf(p2), f2bf(p3) };
                    // P[q][key]: row q=nt*16+ln, key-unit mt*2+(qq>>1), swizzle ^ln
                    *(us4*)&Pseg[(nt * 16 + ln) * 128 + ((mt * 2 + (qq >> 1)) ^ ln) * 8 + (qq & 1) * 4] = pu;
                }
                rs += __shfl_xor(rs, 16);
                rs += __shfl_xor(rs, 32);
                l[nt] = l[nt] * alpha + rs;
                #pragma unroll
                for (int mt = 0; mt < 8; mt++)
                    #pragma unroll
                    for (int r = 0; r < 4; r++)
                        oacc[mt][nt][r] *= alpha;
            }

            // ---- O^T += V^T P^T : A = V^T frags, B = P frags (both LDS) ----
            bf16x8 pf[4][2];
            #pragma unroll
            for (int ks = 0; ks < 4; ks++)
                #pragma unroll
                for (int nt = 0; nt < 2; nt++)
                    pf[ks][nt] = *(const bf16x8*)&Pseg[(nt * 16 + ln) * 128 + ((ks * 4 + qq) ^ ln) * 8];
            __builtin_amdgcn_s_setprio(1);
            #pragma unroll
            for (int mt = 0; mt < 8; mt++) {
                const unsigned short* vr = &KV[16384 + (mt * 16 + ln) * 128];
                bf16x8 vf0 = *(const bf16x8*)&vr[((0 + qq) ^ ln) * 8];
                bf16x8 vf1 = *(const bf16x8*)&vr[((4 + qq) ^ ln) * 8];
                bf16x8 vf2 = *(const bf16x8*)&vr[((8 + qq) ^ ln) * 8];
                bf16x8 vf3 = *(const bf16x8*)&vr[((12 + qq) ^ ln) * 8];
                oacc[mt][0] = MFMA(vf0, pf[0][0], oacc[mt][0]);
                oacc[mt][1] = MFMA(vf0, pf[0][1], oacc[mt][1]);
                oacc[mt][0] = MFMA(vf1, pf[1][0], oacc[mt][0]);
                oacc[mt][1] = MFMA(vf1, pf[1][1], oacc[mt][1]);
                oacc[mt][0] = MFMA(vf2, pf[2][0], oacc[mt][0]);
                oacc[mt][1] = MFMA(vf2, pf[2][1], oacc[mt][1]);
                oacc[mt][0] = MFMA(vf3, pf[3][0], oacc[mt][0]);
                oacc[mt][1] = MFMA(vf3, pf[3][1], oacc[mt][1]);
            }
            __builtin_amdgcn_s_setprio(0);
        }

        // ---- epilogue: lane owns column q; d = mt*16 + qq*4 + r ----
        #pragma unroll
        for (int nt = 0; nt < 2; nt++) {
            const int q = q0 + nt * 16 + ln;
            float inv = 1.f / l[nt];
            unsigned short* ao = aout + ((long)b * SEQ + q) * DIM + h * HDIM;
            #pragma unroll
            for (int mt = 0; mt < 8; mt++) {
                us4 o = { f2bf(oacc[mt][nt][0] * inv), f2bf(oacc[mt][nt][1] * inv),
                          f2bf(oacc[mt][nt][2] * inv), f2bf(oacc[mt][nt][3] * inv) };
                *(us4*)&ao[mt * 16 + qq * 4] = o;
            }
        }
    }
}

// ---------------------------------------------------------------------------
// Output GEMM v4 (kept from round 4 — the "rest" of the iteration improved
// 44 us when the 256-tile pipelines landed): m201-style 256x256, 4 phases
// per K-tile, half-tile staging, vmcnt(6), setprio.  Grid (8,32) = 1/CU.
// ---------------------------------------------------------------------------

// stage one half-tile: operand op (0=A,1=B), half h, K-tile t_, parity p_
#define STAGEH(p_, op_, h_, t_) do {                                              \
    unsigned short* d_ = sh + (p_) * 32768 + (op_) * 16384 + (h_) * 8192 + tid * 8; \
    const unsigned short* s_ = ((op_) ? bg : ag) + (long)((h_) * 128) * K + (t_) * 64; \
    stage16(s_, d_); stage16(s_ + 64 * K, d_ + 4096); } while (0)

#define BARRIER() asm volatile("s_barrier" ::: "memory")
#define WAITLGKM() asm volatile("s_waitcnt lgkmcnt(0)" ::: "memory")

__launch_bounds__(512, 2)
__global__ void out_gemm(const unsigned short* __restrict__ ab,
                         const unsigned short* __restrict__ wt,
                         float* __restrict__ out) {
    constexpr int K  = DIM;
    constexpr int NT = K / 64;
    __shared__ __align__(16) unsigned short sh[65536];
    const int tid = threadIdx.x;
    const int m0 = blockIdx.y * 256;
    const int n0 = blockIdx.x * 256;
    const int w = tid >> 6, lane = tid & 63, qq = lane >> 4, ln = lane & 15;
    const int wm = w >> 2, wn = w & 3;

    f32x4 acc[8][4] = {};

    const int rowq = tid >> 3;
    const int cswz = ((tid & 7) ^ (rowq & 7)) * 8;
    const unsigned short* ag = ab + (long)(m0 + rowq) * K + cswz;
    const unsigned short* bg = wt + (long)(n0 + rowq) * K + cswz;

    const int aoff = wm * 8192 + ln * 64;
    const int boff = 16384 + (wn >> 1) * 8192 + ((wn & 1) * 64 + ln) * 64;
    const int swz0 = ((0 + qq) ^ (ln & 7)) * 8;
    const int swz1 = ((4 + qq) ^ (ln & 7)) * 8;

    STAGEH(0, 1, 0, 0); STAGEH(0, 1, 1, 0); STAGEH(0, 0, 0, 0); STAGEH(0, 0, 1, 0);
    STAGEH(1, 1, 0, 1); STAGEH(1, 0, 0, 1); STAGEH(1, 0, 1, 1);

    #pragma unroll 1
    for (int t = 0; t < NT; t++) {
        const int p = t & 1, pn = p ^ 1;
        if (t >= NT - 1) asm volatile("s_waitcnt vmcnt(0)" ::: "memory");
        else             asm volatile("s_waitcnt vmcnt(6)" ::: "memory");
        BARRIER();

        const unsigned short* Ab = sh + p * 32768;
        bf16x8 af[8][2], bf_[4][2];

        // ---- phase 1
        #pragma unroll
        for (int fc = 0; fc < 4; fc++) {
            bf_[fc][0] = *(const bf16x8*)&Ab[boff + fc * 1024 + swz0];
            bf_[fc][1] = *(const bf16x8*)&Ab[boff + fc * 1024 + swz1];
        }
        #pragma unroll
        for (int fr = 0; fr < 4; fr++) {
            af[fr][0] = *(const bf16x8*)&Ab[aoff + fr * 1024 + swz0];
            af[fr][1] = *(const bf16x8*)&Ab[aoff + fr * 1024 + swz1];
        }
        if (t + 1 < NT) STAGEH(pn, 1, 1, t + 1);
        BARRIER();
        WAITLGKM();
        __builtin_amdgcn_s_setprio(1);
        #pragma unroll
        for (int fr = 0; fr < 4; fr++)
            #pragma unroll
            for (int fc = 0; fc < 2; fc++) {
                acc[fr][fc] = MFMA(af[fr][0], bf_[fc][0], acc[fr][fc]);   // normal C
                acc[fr][fc] = MFMA(af[fr][1], bf_[fc][1], acc[fr][fc]);
            }
        __builtin_amdgcn_s_setprio(0);
        BARRIER();

        // ---- phase 2
        #pragma unroll
        for (int fr = 4; fr < 8; fr++) {
            af[fr][0] = *(const bf16x8*)&Ab[aoff + fr * 1024 + swz0];
            af[fr][1] = *(const bf16x8*)&Ab[aoff + fr * 1024 + swz1];
        }
        if (t + 2 < NT) STAGEH(p, 1, 0, t + 2);
        BARRIER();
        WAITLGKM();
        __builtin_amdgcn_s_setprio(1);
        #pragma unroll
        for (int fr = 0; fr < 4; fr++)
            #pragma unroll
            for (int fc = 2; fc < 4; fc++) {
                acc[fr][fc] = MFMA(af[fr][0], bf_[fc][0], acc[fr][fc]);
                acc[fr][fc] = MFMA(af[fr][1], bf_[fc][1], acc[fr][fc]);
            }
        __builtin_amdgcn_s_setprio(0);
        BARRIER();

        // ---- phase 3
        if (t + 2 < NT) STAGEH(p, 0, 0, t + 2);
        BARRIER();
        __builtin_amdgcn_s_setprio(1);
        #pragma unroll
        for (int fr = 4; fr < 8; fr++)
            #pragma unroll
            for (int fc = 0; fc < 2; fc++) {
                acc[fr][fc] = MFMA(af[fr][0], bf_[fc][0], acc[fr][fc]);
                acc[fr][fc] = MFMA(af[fr][1], bf_[fc][1], acc[fr][fc]);
            }
        __builtin_amdgcn_s_setprio(0);
        BARRIER();

        // ---- phase 4
        if (t + 2 < NT) STAGEH(p, 0, 1, t + 2);
        BARRIER();
        __builtin_amdgcn_s_setprio(1);
        #pragma unroll
        for (int fr = 4; fr < 8; fr++)
            #pragma unroll
            for (int fc = 2; fc < 4; fc++) {
                acc[fr][fc] = MFMA(af[fr][0], bf_[fc][0], acc[fr][fc]);
                acc[fr][fc] = MFMA(af[fr][1], bf_[fc][1], acc[fr][fc]);
            }
        __builtin_amdgcn_s_setprio(0);
        BARRIER();
    }

    // epilogue (normal): m = m0 + wm*128 + fr*16 + qq*4 + r, n = n0 + wn*64 + fc*16 + ln
    for (int fr = 0; fr < 8; fr++)
        for (int fc = 0; fc < 4; fc++) {
            int n = n0 + wn * 64 + fc * 16 + ln;
            for (int r = 0; r < 4; r++) {
                int m = m0 + wm * 128 + fr * 16 + qq * 4 + r;
                out[(long)m * DIM + n] = acc[fr][fc][r];
            }
        }
}

// ---------------------------------------------------------------------------
// Workspace layout: unchanged, total 176,160,768 bytes
// ---------------------------------------------------------------------------
extern "C" void kernel_launch(void* const* d_in, const int* in_sizes, int n_in,
                              void* d_out, int out_size, void* d_ws, size_t ws_size,
                              hipStream_t stream) {
    const float* x    = (const float*)d_in[0];
    const float* wq   = (const float*)d_in[1];
    const float* wk   = (const float*)d_in[2];
    const float* wv   = (const float*)d_in[3];
    const float* wo   = (const float*)d_in[4];
    const float* pcos = (const float*)d_in[5];
    const float* psin = (const float*)d_in[6];
    float* out = (float*)d_out;

    char* ws = (char*)d_ws;
    unsigned short* xb    = (unsigned short*)(ws);
    unsigned short* wqkvt = (unsigned short*)(ws + 33554432L);
    unsigned short* wot   = (unsigned short*)(ws + 50331648L);
    unsigned short* qbuf  = (unsigned short*)(ws + 58720256L);
    unsigned short* kbuf  = (unsigned short*)(ws + 92274688L);
    unsigned short* vbuf  = (unsigned short*)(ws + 109051904L);
    unsigned short* vtb   = (unsigned short*)(ws + 125829120L);
    unsigned short* aout  = (unsigned short*)(ws + 142606336L);

    conv_x<<<16384, 256, 0, stream>>>(x, xb);
    transpose_w<<<dim3(64, 64), dim3(32, 8), 0, stream>>>(wq, wqkvt, 2048, 0);
    transpose_w<<<dim3(32, 64), dim3(32, 8), 0, stream>>>(wk, wqkvt, 1024, 2048);
    transpose_w<<<dim3(32, 64), dim3(32, 8), 0, stream>>>(wv, wqkvt, 1024, 3072);
    transpose_w<<<dim3(64, 64), dim3(32, 8), 0, stream>>>(wo, wot, 2048, 0);

    qkv_gemm<<<dim3(32, 64), 256, 0, stream>>>(xb, wqkvt, pcos, psin, qbuf, kbuf, vbuf);
    transpose_v<<<dim3(4, 64, 32), dim3(32, 8), 0, stream>>>(vbuf, vtb);
    flash<<<dim3(8, 16, 4), 256, 0, stream>>>(qbuf, kbuf, vtb, aout);
    out_gemm<<<dim3(8, 32), 512, 0, stream>>>(aout, wot, out);
}

// Round 6
// 505.133 us; speedup vs baseline: 1.0784x; 1.0784x over previous
//
#include <hip/hip_runtime.h>
#include <stdint.h>

// ---------------------------------------------------------------------------
// Problem constants: B=4, S=2048, D=2048, H=16, KVH=8, HD=128, N_REP=2
// ---------------------------------------------------------------------------
#define SEQ   2048
#define DIM   2048
#define NH    16
#define NKVH  8
#define HDIM  128
#define MTOT  8192      // B*S
#define LOG2E 1.44269504088896340736f

typedef short bf16x8 __attribute__((ext_vector_type(8)));   // 8 bf16 = 4 VGPRs
typedef float f32x4  __attribute__((ext_vector_type(4)));
typedef unsigned short us4 __attribute__((ext_vector_type(4)));

#define MFMA(a, b, c) __builtin_amdgcn_mfma_f32_16x16x32_bf16((a), (b), (c), 0, 0, 0)

__device__ inline unsigned short f2bf(float f) {
    unsigned u = __builtin_bit_cast(unsigned, f);
    u = (u + 0x7FFFu + ((u >> 16) & 1u)) >> 16;   // RNE
    return (unsigned short)u;
}

__device__ inline void stage16(const void* g, void* l) {
    __builtin_amdgcn_global_load_lds(
        (const __attribute__((address_space(1))) void*)g,
        (__attribute__((address_space(3))) void*)l,
        16, 0, 0);
}

// ---------------------------------------------------------------------------
// Prep: x f32 -> bf16
// ---------------------------------------------------------------------------
__global__ void conv_x(const float* __restrict__ x, unsigned short* __restrict__ xb) {
    long i = ((long)blockIdx.x * 256 + threadIdx.x) * 4;
    float4 v = *(const float4*)(x + i);
    us4 o = { f2bf(v.x), f2bf(v.y), f2bf(v.z), f2bf(v.w) };
    *(us4*)(xb + i) = o;
}

// ---------------------------------------------------------------------------
// Prep: weight (K=2048 rows x N cols, f32) -> transposed bf16 [N][2048]
// ---------------------------------------------------------------------------
__global__ void transpose_w(const float* __restrict__ in, unsigned short* __restrict__ out,
                            int N, int row_off) {
    __shared__ float t[32][33];
    int tx = threadIdx.x, ty = threadIdx.y;
    int n0 = blockIdx.x * 32, k0 = blockIdx.y * 32;
    for (int i = 0; i < 4; i++)
        t[ty + i * 8][tx] = in[(long)(k0 + ty + i * 8) * N + n0 + tx];
    __syncthreads();
    for (int i = 0; i < 4; i++)
        out[(long)(row_off + n0 + ty + i * 8) * 2048 + k0 + tx] = f2bf(t[tx][ty + i * 8]);
}

// ---------------------------------------------------------------------------
// Prep: V (b,kvh,s,hd) bf16 -> V^T (b,kvh,hd,s) bf16
// ---------------------------------------------------------------------------
__global__ void transpose_v(const unsigned short* __restrict__ v, unsigned short* __restrict__ vt) {
    __shared__ unsigned short t[32][33];
    int tx = threadIdx.x, ty = threadIdx.y;
    int d0 = blockIdx.x * 32, s0 = blockIdx.y * 32, bk = blockIdx.z;
    const unsigned short* vin = v + (long)bk * SEQ * HDIM;
    unsigned short* vo = vt + (long)bk * HDIM * SEQ;
    for (int i = 0; i < 4; i++)
        t[ty + i * 8][tx] = vin[(long)(s0 + ty + i * 8) * HDIM + d0 + tx];
    __syncthreads();
    for (int i = 0; i < 4; i++)
        vo[(long)(d0 + ty + i * 8) * SEQ + s0 + tx] = t[tx][ty + i * 8];
}

// ---------------------------------------------------------------------------
// QKV GEMM (empirically best: 152 us / 42% MfmaUtil): BK=64, 128x128 tile,
// 256 threads, single-buffer 2-sync schedule, ~3-4 blocks/CU implicit
// cross-block overlap.  XOR-swizzled LDS, C^T orientation, in-lane RoPE.
// ---------------------------------------------------------------------------
__launch_bounds__(256, 2)
__global__ void qkv_gemm(const unsigned short* __restrict__ xb,
                         const unsigned short* __restrict__ wt,
                         const float* __restrict__ pcos, const float* __restrict__ psin,
                         unsigned short* __restrict__ qb, unsigned short* __restrict__ kbuf,
                         unsigned short* __restrict__ vbuf) {
    constexpr int K = DIM;
    __shared__ __align__(16) unsigned short As[128 * 64];
    __shared__ __align__(16) unsigned short Bs[128 * 64];
    const int tid = threadIdx.x;
    const int m0 = blockIdx.y * 128;
    const int n0 = blockIdx.x * 128;
    const int w = tid >> 6, lane = tid & 63, qq = lane >> 4, ln = lane & 15;
    const int wm = w >> 1, wn = w & 1;

    f32x4 acc[4][4] = {};

    const int arow = tid >> 3;                          // 0..31 (row within 32-row round)
    const int aswz = ((tid & 7) ^ (arow & 7)) * 8;      // swizzled source col (shorts)
    const unsigned short* ag = xb + (long)(m0 + arow) * K + aswz;
    const unsigned short* bg = wt + (long)(n0 + arow) * K + aswz;
    unsigned short* al = As + tid * 8;
    unsigned short* bl = Bs + tid * 8;

    for (int kk = 0; kk < K; kk += 64) {
        __syncthreads();
        stage16(ag + kk,          al);
        stage16(ag + kk + 32 * K, al + 2048);
        stage16(ag + kk + 64 * K, al + 4096);
        stage16(ag + kk + 96 * K, al + 6144);
        stage16(bg + kk,          bl);
        stage16(bg + kk + 32 * K, bl + 2048);
        stage16(bg + kk + 64 * K, bl + 4096);
        stage16(bg + kk + 96 * K, bl + 6144);
        __syncthreads();
        bf16x8 a[2][4], b[2][4];
        for (int ks = 0; ks < 2; ks++) {
            for (int mt = 0; mt < 4; mt++)
                a[ks][mt] = *(const bf16x8*)&As[(wm * 64 + mt * 16 + ln) * 64 + (((ks * 4 + qq) ^ (ln & 7)) * 8)];
            for (int nt = 0; nt < 4; nt++)
                b[ks][nt] = *(const bf16x8*)&Bs[(wn * 64 + nt * 16 + ln) * 64 + (((ks * 4 + qq) ^ (ln & 7)) * 8)];
        }
        for (int ks = 0; ks < 2; ks++)
            for (int mt = 0; mt < 4; mt++)
                for (int nt = 0; nt < 4; nt++)
                    acc[mt][nt] = MFMA(b[ks][nt], a[ks][mt], acc[mt][nt]);   // C^T
    }

    // epilogue: n = n0 + wn*64 + nt*16 + qq*4 + r (regs), m = m0 + wm*64 + mt*16 + ln
    const bool isv = (n0 >= 3072);          // block-uniform: no RoPE for v
    for (int mt = 0; mt < 4; mt++) {
        int m = m0 + wm * 64 + mt * 16 + ln;
        int b_ = m >> 11, s = m & (SEQ - 1);
        const float* crow = pcos + s * 64;
        const float* srow = psin + s * 64;
        for (int nt = 0; nt < 4; nt++) {
            int n = n0 + wn * 64 + nt * 16 + qq * 4;
            int d = n & (HDIM - 1);
            f32x4 v = acc[mt][nt];
            float o0, o1, o2, o3;
            if (!isv) {                      // RoPE, pairs in-lane
                int i = d >> 1;
                float2 cc = *(const float2*)(crow + i);
                float2 ss = *(const float2*)(srow + i);
                o0 = v[0] * cc.x - v[1] * ss.x;
                o1 = v[0] * ss.x + v[1] * cc.x;
                o2 = v[2] * cc.y - v[3] * ss.y;
                o3 = v[2] * ss.y + v[3] * cc.y;
            } else {
                o0 = v[0]; o1 = v[1]; o2 = v[2]; o3 = v[3];
            }
            us4 pu = { f2bf(o0), f2bf(o1), f2bf(o2), f2bf(o3) };
            if (n < 2048) {
                int hh = n >> 7;
                *(us4*)&qb[((long)(b_ * NH + hh) * SEQ + s) * HDIM + d] = pu;
            } else if (n < 3072) {
                int kvh = (n - 2048) >> 7;
                *(us4*)&kbuf[((long)(b_ * NKVH + kvh) * SEQ + s) * HDIM + d] = pu;
            } else {
                int kvh = (n - 3072) >> 7;
                *(us4*)&vbuf[((long)(b_ * NKVH + kvh) * SEQ + s) * HDIM + d] = pu;
            }
        }
    }
}

// ---------------------------------------------------------------------------
// Flash attention v3b (setprio REMOVED — r5 A/B showed it cost ~+44 us:
// prioritizing one block's MFMA starves the co-resident block's staging
// issue, destroying the cross-block overlap that makes this kernel fast).
// ---------------------------------------------------------------------------
__launch_bounds__(256, 2)
__global__ void flash(const unsigned short* __restrict__ qb,
                      const unsigned short* __restrict__ kb,
                      const unsigned short* __restrict__ vtb,
                      unsigned short* __restrict__ aout) {
    __shared__ __align__(16) unsigned short KV[32768];   // K: shorts [0,16384)  V^T: [16384,32768)
    const int tid = threadIdx.x;
    const int w = tid >> 6, lane = tid & 63, qq = lane >> 4, ln = lane & 15;
    unsigned short* Pseg = KV + w * 4096;                // P overlay, wave-private 8 KB

    // block swizzle: XCD = flat%8; pin 4 (b,kv) pairs per XCD
    int f = blockIdx.x + (blockIdx.y << 3) + (blockIdx.z << 7);  // grid (8,16,4)
    int xcd = f & 7, j = f >> 3;
    int bkv = xcd + 8 * (j & 3);
    int b = bkv >> 3, kv = bkv & 7;
    int rem = j >> 2;
    int h = kv * 2 + (rem & 1);
    int qpair = rem >> 1;

    const unsigned short* qbase = qb + (long)(b * NH + h) * SEQ * HDIM;
    const unsigned short* kbase = kb + (long)(b * NKVH + kv) * SEQ * HDIM;
    const unsigned short* vbase = vtb + (long)(b * NKVH + kv) * HDIM * SEQ;
    const float SCL2 = 0.088388347648318447f * LOG2E;   // scale * log2(e), folded

    const int srow = tid >> 4;                 // staging: row within 16-row group
    const int sswz = (tid & 15) ^ srow;        // staging: swizzled source unit

    for (int phase = 0; phase < 2; phase++) {
        const int qt = (phase == 0) ? qpair : 15 - qpair;
        const int q0 = qt * 128 + w * 32;

        // Q fragments (B-operand layout: lane=q, k-contiguous)
        bf16x8 qf[2][4];
        for (int nt = 0; nt < 2; nt++)
            for (int ks = 0; ks < 4; ks++)
                qf[nt][ks] = *(const bf16x8*)&qbase[(long)(q0 + nt * 16 + ln) * HDIM + ks * 32 + qq * 8];

        float m[2] = { -3e38f, -3e38f }, l[2] = { 0.f, 0.f };
        f32x4 oacc[8][2] = {};

        #pragma unroll 1
        for (int kt = 0; kt <= qt; kt++) {
            const int k0 = kt * 128;

            __syncthreads();   // B_pre: everyone done reading previous K/V/P
            // stage K [key][hd-unit^swz] and V^T [hd][key-unit^swz]
            char* kl = (char*)KV;
            #pragma unroll
            for (int r = 0; r < 8; r++) {
                int key = r * 16 + srow;
                stage16(kbase + (long)(k0 + key) * HDIM + sswz * 8, kl + r * 4096 + tid * 16);
            }
            #pragma unroll
            for (int r = 0; r < 8; r++) {
                int hd = r * 16 + srow;
                stage16(vbase + (long)hd * SEQ + k0 + sswz * 8, kl + 32768 + r * 4096 + tid * 16);
            }
            __syncthreads();   // B_vis: compiler's vmcnt(0) drain + visibility

            // ---- S^T = K Q^T : A-frags from swizzled LDS ----
            f32x4 sacc[8][2] = {};
            #pragma unroll
            for (int mt = 0; mt < 8; mt++) {
                const unsigned short* kr = &KV[(mt * 16 + ln) * 128];
                bf16x8 kf0 = *(const bf16x8*)&kr[((0 + qq) ^ ln) * 8];
                bf16x8 kf1 = *(const bf16x8*)&kr[((4 + qq) ^ ln) * 8];
                bf16x8 kf2 = *(const bf16x8*)&kr[((8 + qq) ^ ln) * 8];
                bf16x8 kf3 = *(const bf16x8*)&kr[((12 + qq) ^ ln) * 8];
                sacc[mt][0] = MFMA(kf0, qf[0][0], sacc[mt][0]);
                sacc[mt][1] = MFMA(kf0, qf[1][0], sacc[mt][1]);
                sacc[mt][0] = MFMA(kf1, qf[0][1], sacc[mt][0]);
                sacc[mt][1] = MFMA(kf1, qf[1][1], sacc[mt][1]);
                sacc[mt][0] = MFMA(kf2, qf[0][2], sacc[mt][0]);
                sacc[mt][1] = MFMA(kf2, qf[1][2], sacc[mt][1]);
                sacc[mt][0] = MFMA(kf3, qf[0][3], sacc[mt][0]);
                sacc[mt][1] = MFMA(kf3, qf[1][3], sacc[mt][1]);
            }

            __syncthreads();   // B_k: all waves done reading K region (P overlays it)

            // ---- online softmax in raw units (scale folded into SCL2) ----
            const bool diag = (kt == qt);
            #pragma unroll
            for (int nt = 0; nt < 2; nt++) {
                const int q = q0 + nt * 16 + ln;
                float mx = m[nt];
                #pragma unroll
                for (int mt = 0; mt < 8; mt++)
                    #pragma unroll
                    for (int r = 0; r < 4; r++) {
                        float v = sacc[mt][nt][r];
                        if (diag && (k0 + mt * 16 + qq * 4 + r > q)) v = -3e38f;
                        sacc[mt][nt][r] = v;
                        mx = fmaxf(mx, v);
                    }
                mx = fmaxf(mx, __shfl_xor(mx, 16));
                mx = fmaxf(mx, __shfl_xor(mx, 32));
                float alpha = exp2f((m[nt] - mx) * SCL2);
                m[nt] = mx;
                float rs = 0.f;
                #pragma unroll
                for (int mt = 0; mt < 8; mt++) {
                    float p0 = exp2f((sacc[mt][nt][0] - mx) * SCL2);
                    float p1 = exp2f((sacc[mt][nt][1] - mx) * SCL2);
                    float p2 = exp2f((sacc[mt][nt][2] - mx) * SCL2);
                    float p3 = exp2f((sacc[mt][nt][3] - mx) * SCL2);
                    rs += (p0 + p1) + (p2 + p3);
                    us4 pu = { f2bf(p0), f2bf(p1), f2bf(p2), f2bf(p3) };
                    // P[q][key]: row q=nt*16+ln, key-unit mt*2+(qq>>1), swizzle ^ln
                    *(us4*)&Pseg[(nt * 16 + ln) * 128 + ((mt * 2 + (qq >> 1)) ^ ln) * 8 + (qq & 1) * 4] = pu;
                }
                rs += __shfl_xor(rs, 16);
                rs += __shfl_xor(rs, 32);
                l[nt] = l[nt] * alpha + rs;
                #pragma unroll
                for (int mt = 0; mt < 8; mt++)
                    #pragma unroll
                    for (int r = 0; r < 4; r++)
                        oacc[mt][nt][r] *= alpha;
            }

            // ---- O^T += V^T P^T : A = V^T frags, B = P frags (both LDS) ----
            bf16x8 pf[4][2];
            #pragma unroll
            for (int ks = 0; ks < 4; ks++)
                #pragma unroll
                for (int nt = 0; nt < 2; nt++)
                    pf[ks][nt] = *(const bf16x8*)&Pseg[(nt * 16 + ln) * 128 + ((ks * 4 + qq) ^ ln) * 8];
            #pragma unroll
            for (int mt = 0; mt < 8; mt++) {
                const unsigned short* vr = &KV[16384 + (mt * 16 + ln) * 128];
                bf16x8 vf0 = *(const bf16x8*)&vr[((0 + qq) ^ ln) * 8];
                bf16x8 vf1 = *(const bf16x8*)&vr[((4 + qq) ^ ln) * 8];
                bf16x8 vf2 = *(const bf16x8*)&vr[((8 + qq) ^ ln) * 8];
                bf16x8 vf3 = *(const bf16x8*)&vr[((12 + qq) ^ ln) * 8];
                oacc[mt][0] = MFMA(vf0, pf[0][0], oacc[mt][0]);
                oacc[mt][1] = MFMA(vf0, pf[0][1], oacc[mt][1]);
                oacc[mt][0] = MFMA(vf1, pf[1][0], oacc[mt][0]);
                oacc[mt][1] = MFMA(vf1, pf[1][1], oacc[mt][1]);
                oacc[mt][0] = MFMA(vf2, pf[2][0], oacc[mt][0]);
                oacc[mt][1] = MFMA(vf2, pf[2][1], oacc[mt][1]);
                oacc[mt][0] = MFMA(vf3, pf[3][0], oacc[mt][0]);
                oacc[mt][1] = MFMA(vf3, pf[3][1], oacc[mt][1]);
            }
        }

        // ---- epilogue: lane owns column q; d = mt*16 + qq*4 + r ----
        #pragma unroll
        for (int nt = 0; nt < 2; nt++) {
            const int q = q0 + nt * 16 + ln;
            float inv = 1.f / l[nt];
            unsigned short* ao = aout + ((long)b * SEQ + q) * DIM + h * HDIM;
            #pragma unroll
            for (int mt = 0; mt < 8; mt++) {
                us4 o = { f2bf(oacc[mt][nt][0] * inv), f2bf(oacc[mt][nt][1] * inv),
                          f2bf(oacc[mt][nt][2] * inv), f2bf(oacc[mt][nt][3] * inv) };
                *(us4*)&ao[mt * 16 + qq * 4] = o;
            }
        }
    }
}

// ---------------------------------------------------------------------------
// Output GEMM v4 (kept — part of the measured-best 348.6 us rest): m201-style
// 256x256, 4 phases per K-tile, half-tile staging, vmcnt(6), setprio.
// Grid (8,32) = 1 block/CU.
// ---------------------------------------------------------------------------

// stage one half-tile: operand op (0=A,1=B), half h, K-tile t_, parity p_
#define STAGEH(p_, op_, h_, t_) do {                                              \
    unsigned short* d_ = sh + (p_) * 32768 + (op_) * 16384 + (h_) * 8192 + tid * 8; \
    const unsigned short* s_ = ((op_) ? bg : ag) + (long)((h_) * 128) * K + (t_) * 64; \
    stage16(s_, d_); stage16(s_ + 64 * K, d_ + 4096); } while (0)

#define BARRIER() asm volatile("s_barrier" ::: "memory")
#define WAITLGKM() asm volatile("s_waitcnt lgkmcnt(0)" ::: "memory")

__launch_bounds__(512, 2)
__global__ void out_gemm(const unsigned short* __restrict__ ab,
                         const unsigned short* __restrict__ wt,
                         float* __restrict__ out) {
    constexpr int K  = DIM;
    constexpr int NT = K / 64;
    __shared__ __align__(16) unsigned short sh[65536];
    const int tid = threadIdx.x;
    const int m0 = blockIdx.y * 256;
    const int n0 = blockIdx.x * 256;
    const int w = tid >> 6, lane = tid & 63, qq = lane >> 4, ln = lane & 15;
    const int wm = w >> 2, wn = w & 3;

    f32x4 acc[8][4] = {};

    const int rowq = tid >> 3;
    const int cswz = ((tid & 7) ^ (rowq & 7)) * 8;
    const unsigned short* ag = ab + (long)(m0 + rowq) * K + cswz;
    const unsigned short* bg = wt + (long)(n0 + rowq) * K + cswz;

    const int aoff = wm * 8192 + ln * 64;
    const int boff = 16384 + (wn >> 1) * 8192 + ((wn & 1) * 64 + ln) * 64;
    const int swz0 = ((0 + qq) ^ (ln & 7)) * 8;
    const int swz1 = ((4 + qq) ^ (ln & 7)) * 8;

    STAGEH(0, 1, 0, 0); STAGEH(0, 1, 1, 0); STAGEH(0, 0, 0, 0); STAGEH(0, 0, 1, 0);
    STAGEH(1, 1, 0, 1); STAGEH(1, 0, 0, 1); STAGEH(1, 0, 1, 1);

    #pragma unroll 1
    for (int t = 0; t < NT; t++) {
        const int p = t & 1, pn = p ^ 1;
        if (t >= NT - 1) asm volatile("s_waitcnt vmcnt(0)" ::: "memory");
        else             asm volatile("s_waitcnt vmcnt(6)" ::: "memory");
        BARRIER();

        const unsigned short* Ab = sh + p * 32768;
        bf16x8 af[8][2], bf_[4][2];

        // ---- phase 1
        #pragma unroll
        for (int fc = 0; fc < 4; fc++) {
            bf_[fc][0] = *(const bf16x8*)&Ab[boff + fc * 1024 + swz0];
            bf_[fc][1] = *(const bf16x8*)&Ab[boff + fc * 1024 + swz1];
        }
        #pragma unroll
        for (int fr = 0; fr < 4; fr++) {
            af[fr][0] = *(const bf16x8*)&Ab[aoff + fr * 1024 + swz0];
            af[fr][1] = *(const bf16x8*)&Ab[aoff + fr * 1024 + swz1];
        }
        if (t + 1 < NT) STAGEH(pn, 1, 1, t + 1);
        BARRIER();
        WAITLGKM();
        __builtin_amdgcn_s_setprio(1);
        #pragma unroll
        for (int fr = 0; fr < 4; fr++)
            #pragma unroll
            for (int fc = 0; fc < 2; fc++) {
                acc[fr][fc] = MFMA(af[fr][0], bf_[fc][0], acc[fr][fc]);   // normal C
                acc[fr][fc] = MFMA(af[fr][1], bf_[fc][1], acc[fr][fc]);
            }
        __builtin_amdgcn_s_setprio(0);
        BARRIER();

        // ---- phase 2
        #pragma unroll
        for (int fr = 4; fr < 8; fr++) {
            af[fr][0] = *(const bf16x8*)&Ab[aoff + fr * 1024 + swz0];
            af[fr][1] = *(const bf16x8*)&Ab[aoff + fr * 1024 + swz1];
        }
        if (t + 2 < NT) STAGEH(p, 1, 0, t + 2);
        BARRIER();
        WAITLGKM();
        __builtin_amdgcn_s_setprio(1);
        #pragma unroll
        for (int fr = 0; fr < 4; fr++)
            #pragma unroll
            for (int fc = 2; fc < 4; fc++) {
                acc[fr][fc] = MFMA(af[fr][0], bf_[fc][0], acc[fr][fc]);
                acc[fr][fc] = MFMA(af[fr][1], bf_[fc][1], acc[fr][fc]);
            }
        __builtin_amdgcn_s_setprio(0);
        BARRIER();

        // ---- phase 3
        if (t + 2 < NT) STAGEH(p, 0, 0, t + 2);
        BARRIER();
        __builtin_amdgcn_s_setprio(1);
        #pragma unroll
        for (int fr = 4; fr < 8; fr++)
            #pragma unroll
            for (int fc = 0; fc < 2; fc++) {
                acc[fr][fc] = MFMA(af[fr][0], bf_[fc][0], acc[fr][fc]);
                acc[fr][fc] = MFMA(af[fr][1], bf_[fc][1], acc[fr][fc]);
            }
        __builtin_amdgcn_s_setprio(0);
        BARRIER();

        // ---- phase 4
        if (t + 2 < NT) STAGEH(p, 0, 1, t + 2);
        BARRIER();
        __builtin_amdgcn_s_setprio(1);
        #pragma unroll
        for (int fr = 4; fr < 8; fr++)
            #pragma unroll
            for (int fc = 2; fc < 4; fc++) {
                acc[fr][fc] = MFMA(af[fr][0], bf_[fc][0], acc[fr][fc]);
                acc[fr][fc] = MFMA(af[fr][1], bf_[fc][1], acc[fr][fc]);
            }
        __builtin_amdgcn_s_setprio(0);
        BARRIER();
    }

    // epilogue (normal): m = m0 + wm*128 + fr*16 + qq*4 + r, n = n0 + wn*64 + fc*16 + ln
    for (int fr = 0; fr < 8; fr++)
        for (int fc = 0; fc < 4; fc++) {
            int n = n0 + wn * 64 + fc * 16 + ln;
            for (int r = 0; r < 4; r++) {
                int m = m0 + wm * 128 + fr * 16 + qq * 4 + r;
                out[(long)m * DIM + n] = acc[fr][fc][r];
            }
        }
}

// ---------------------------------------------------------------------------
// Workspace layout: unchanged, total 176,160,768 bytes
// ---------------------------------------------------------------------------
extern "C" void kernel_launch(void* const* d_in, const int* in_sizes, int n_in,
                              void* d_out, int out_size, void* d_ws, size_t ws_size,
                              hipStream_t stream) {
    const float* x    = (const float*)d_in[0];
    const float* wq   = (const float*)d_in[1];
    const float* wk   = (const float*)d_in[2];
    const float* wv   = (const float*)d_in[3];
    const float* wo   = (const float*)d_in[4];
    const float* pcos = (const float*)d_in[5];
    const float* psin = (const float*)d_in[6];
    float* out = (float*)d_out;

    char* ws = (char*)d_ws;
    unsigned short* xb    = (unsigned short*)(ws);
    unsigned short* wqkvt = (unsigned short*)(ws + 33554432L);
    unsigned short* wot   = (unsigned short*)(ws + 50331648L);
    unsigned short* qbuf  = (unsigned short*)(ws + 58720256L);
    unsigned short* kbuf  = (unsigned short*)(ws + 92274688L);
    unsigned short* vbuf  = (unsigned short*)(ws + 109051904L);
    unsigned short* vtb   = (unsigned short*)(ws + 125829120L);
    unsigned short* aout  = (unsigned short*)(ws + 142606336L);

    conv_x<<<16384, 256, 0, stream>>>(x, xb);
    transpose_w<<<dim3(64, 64), dim3(32, 8), 0, stream>>>(wq, wqkvt, 2048, 0);
    transpose_w<<<dim3(32, 64), dim3(32, 8), 0, stream>>>(wk, wqkvt, 1024, 2048);
    transpose_w<<<dim3(32, 64), dim3(32, 8), 0, stream>>>(wv, wqkvt, 1024, 3072);
    transpose_w<<<dim3(64, 64), dim3(32, 8), 0, stream>>>(wo, wot, 2048, 0);

    qkv_gemm<<<dim3(32, 64), 256, 0, stream>>>(xb, wqkvt, pcos, psin, qbuf, kbuf, vbuf);
    transpose_v<<<dim3(4, 64, 32), dim3(32, 8), 0, stream>>>(vbuf, vtb);
    flash<<<dim3(8, 16, 4), 256, 0, stream>>>(qbuf, kbuf, vtb, aout);
    out_gemm<<<dim3(8, 32), 512, 0, stream>>>(aout, wot, out);
}

// Round 7
// 489.106 us; speedup vs baseline: 1.1137x; 1.0328x over previous
//
#include <hip/hip_runtime.h>
#include <stdint.h>

// ---------------------------------------------------------------------------
// Problem constants: B=4, S=2048, D=2048, H=16, KVH=8, HD=128, N_REP=2
// ---------------------------------------------------------------------------
#define SEQ   2048
#define DIM   2048
#define NH    16
#define NKVH  8
#define HDIM  128
#define MTOT  8192      // B*S
#define LOG2E 1.44269504088896340736f

typedef short bf16x8 __attribute__((ext_vector_type(8)));   // 8 bf16 = 4 VGPRs
typedef float f32x4  __attribute__((ext_vector_type(4)));
typedef unsigned short us4 __attribute__((ext_vector_type(4)));

#define MFMA(a, b, c) __builtin_amdgcn_mfma_f32_16x16x32_bf16((a), (b), (c), 0, 0, 0)

__device__ inline unsigned short f2bf(float f) {
    unsigned u = __builtin_bit_cast(unsigned, f);
    u = (u + 0x7FFFu + ((u >> 16) & 1u)) >> 16;   // RNE
    return (unsigned short)u;
}

__device__ inline void stage16(const void* g, void* l) {
    __builtin_amdgcn_global_load_lds(
        (const __attribute__((address_space(1))) void*)g,
        (__attribute__((address_space(3))) void*)l,
        16, 0, 0);
}

// ---------------------------------------------------------------------------
// Prep: x f32 -> bf16
// ---------------------------------------------------------------------------
__global__ void conv_x(const float* __restrict__ x, unsigned short* __restrict__ xb) {
    long i = ((long)blockIdx.x * 256 + threadIdx.x) * 4;
    float4 v = *(const float4*)(x + i);
    us4 o = { f2bf(v.x), f2bf(v.y), f2bf(v.z), f2bf(v.w) };
    *(us4*)(xb + i) = o;
}

// ---------------------------------------------------------------------------
// Prep: weight (K=2048 rows x N cols, f32) -> transposed bf16 [N][2048]
// ---------------------------------------------------------------------------
__global__ void transpose_w(const float* __restrict__ in, unsigned short* __restrict__ out,
                            int N, int row_off) {
    __shared__ float t[32][33];
    int tx = threadIdx.x, ty = threadIdx.y;
    int n0 = blockIdx.x * 32, k0 = blockIdx.y * 32;
    for (int i = 0; i < 4; i++)
        t[ty + i * 8][tx] = in[(long)(k0 + ty + i * 8) * N + n0 + tx];
    __syncthreads();
    for (int i = 0; i < 4; i++)
        out[(long)(row_off + n0 + ty + i * 8) * 2048 + k0 + tx] = f2bf(t[tx][ty + i * 8]);
}

// ---------------------------------------------------------------------------
// Prep: V (b,kvh,s,hd) bf16 -> V^T (b,kvh,hd,s) bf16
// ---------------------------------------------------------------------------
__global__ void transpose_v(const unsigned short* __restrict__ v, unsigned short* __restrict__ vt) {
    __shared__ unsigned short t[32][33];
    int tx = threadIdx.x, ty = threadIdx.y;
    int d0 = blockIdx.x * 32, s0 = blockIdx.y * 32, bk = blockIdx.z;
    const unsigned short* vin = v + (long)bk * SEQ * HDIM;
    unsigned short* vo = vt + (long)bk * HDIM * SEQ;
    for (int i = 0; i < 4; i++)
        t[ty + i * 8][tx] = vin[(long)(s0 + ty + i * 8) * HDIM + d0 + tx];
    __syncthreads();
    for (int i = 0; i < 4; i++)
        vo[(long)(d0 + ty + i * 8) * SEQ + s0 + tx] = t[tx][ty + i * 8];
}

// ---------------------------------------------------------------------------
// QKV GEMM (empirically best: ~148 us / 42% MfmaUtil): BK=64, 128x128 tile,
// 256 threads, single-buffer 2-sync schedule, ~3-4 blocks/CU implicit
// cross-block overlap.  XOR-swizzled LDS, C^T orientation, in-lane RoPE.
// ---------------------------------------------------------------------------
__launch_bounds__(256, 2)
__global__ void qkv_gemm(const unsigned short* __restrict__ xb,
                         const unsigned short* __restrict__ wt,
                         const float* __restrict__ pcos, const float* __restrict__ psin,
                         unsigned short* __restrict__ qb, unsigned short* __restrict__ kbuf,
                         unsigned short* __restrict__ vbuf) {
    constexpr int K = DIM;
    __shared__ __align__(16) unsigned short As[128 * 64];
    __shared__ __align__(16) unsigned short Bs[128 * 64];
    const int tid = threadIdx.x;
    const int m0 = blockIdx.y * 128;
    const int n0 = blockIdx.x * 128;
    const int w = tid >> 6, lane = tid & 63, qq = lane >> 4, ln = lane & 15;
    const int wm = w >> 1, wn = w & 1;

    f32x4 acc[4][4] = {};

    const int arow = tid >> 3;                          // 0..31 (row within 32-row round)
    const int aswz = ((tid & 7) ^ (arow & 7)) * 8;      // swizzled source col (shorts)
    const unsigned short* ag = xb + (long)(m0 + arow) * K + aswz;
    const unsigned short* bg = wt + (long)(n0 + arow) * K + aswz;
    unsigned short* al = As + tid * 8;
    unsigned short* bl = Bs + tid * 8;

    for (int kk = 0; kk < K; kk += 64) {
        __syncthreads();
        stage16(ag + kk,          al);
        stage16(ag + kk + 32 * K, al + 2048);
        stage16(ag + kk + 64 * K, al + 4096);
        stage16(ag + kk + 96 * K, al + 6144);
        stage16(bg + kk,          bl);
        stage16(bg + kk + 32 * K, bl + 2048);
        stage16(bg + kk + 64 * K, bl + 4096);
        stage16(bg + kk + 96 * K, bl + 6144);
        __syncthreads();
        bf16x8 a[2][4], b[2][4];
        for (int ks = 0; ks < 2; ks++) {
            for (int mt = 0; mt < 4; mt++)
                a[ks][mt] = *(const bf16x8*)&As[(wm * 64 + mt * 16 + ln) * 64 + (((ks * 4 + qq) ^ (ln & 7)) * 8)];
            for (int nt = 0; nt < 4; nt++)
                b[ks][nt] = *(const bf16x8*)&Bs[(wn * 64 + nt * 16 + ln) * 64 + (((ks * 4 + qq) ^ (ln & 7)) * 8)];
        }
        for (int ks = 0; ks < 2; ks++)
            for (int mt = 0; mt < 4; mt++)
                for (int nt = 0; nt < 4; nt++)
                    acc[mt][nt] = MFMA(b[ks][nt], a[ks][mt], acc[mt][nt]);   // C^T
    }

    // epilogue: n = n0 + wn*64 + nt*16 + qq*4 + r (regs), m = m0 + wm*64 + mt*16 + ln
    const bool isv = (n0 >= 3072);          // block-uniform: no RoPE for v
    for (int mt = 0; mt < 4; mt++) {
        int m = m0 + wm * 64 + mt * 16 + ln;
        int b_ = m >> 11, s = m & (SEQ - 1);
        const float* crow = pcos + s * 64;
        const float* srow = psin + s * 64;
        for (int nt = 0; nt < 4; nt++) {
            int n = n0 + wn * 64 + nt * 16 + qq * 4;
            int d = n & (HDIM - 1);
            f32x4 v = acc[mt][nt];
            float o0, o1, o2, o3;
            if (!isv) {                      // RoPE, pairs in-lane
                int i = d >> 1;
                float2 cc = *(const float2*)(crow + i);
                float2 ss = *(const float2*)(srow + i);
                o0 = v[0] * cc.x - v[1] * ss.x;
                o1 = v[0] * ss.x + v[1] * cc.x;
                o2 = v[2] * cc.y - v[3] * ss.y;
                o3 = v[2] * ss.y + v[3] * cc.y;
            } else {
                o0 = v[0]; o1 = v[1]; o2 = v[2]; o3 = v[3];
            }
            us4 pu = { f2bf(o0), f2bf(o1), f2bf(o2), f2bf(o3) };
            if (n < 2048) {
                int hh = n >> 7;
                *(us4*)&qb[((long)(b_ * NH + hh) * SEQ + s) * HDIM + d] = pu;
            } else if (n < 3072) {
                int kvh = (n - 2048) >> 7;
                *(us4*)&kbuf[((long)(b_ * NKVH + kvh) * SEQ + s) * HDIM + d] = pu;
            } else {
                int kvh = (n - 3072) >> 7;
                *(us4*)&vbuf[((long)(b_ * NKVH + kvh) * SEQ + s) * HDIM + d] = pu;
            }
        }
    }
}

// ---------------------------------------------------------------------------
// Flash attention v4: split K/V waits (cp.async-style counted vmcnt):
//   stage K then V; vmcnt(8)+bar -> K resident, QK^T runs while V in flight;
//   lgkmcnt(0)+bar -> K reads done, P overlay safe (V still in flight);
//   softmax (V latency hides under QK^T + softmax);
//   vmcnt(0)+bar -> V resident; PV.
// Plus defer-max (T13): skip O-rescale while tile max within 62.7 raw units
// (exp2 exponent <= 8, p <= 256 — bf16-safe).  No setprio (r5: −44 us).
// ---------------------------------------------------------------------------
__launch_bounds__(256, 2)
__global__ void flash(const unsigned short* __restrict__ qb,
                      const unsigned short* __restrict__ kb,
                      const unsigned short* __restrict__ vtb,
                      unsigned short* __restrict__ aout) {
    __shared__ __align__(16) unsigned short KV[32768];   // K: shorts [0,16384)  V^T: [16384,32768)
    const int tid = threadIdx.x;
    const int w = tid >> 6, lane = tid & 63, qq = lane >> 4, ln = lane & 15;
    unsigned short* Pseg = KV + w * 4096;                // P overlay, wave-private 8 KB

    // block swizzle: XCD = flat%8; pin 4 (b,kv) pairs per XCD
    int f = blockIdx.x + (blockIdx.y << 3) + (blockIdx.z << 7);  // grid (8,16,4)
    int xcd = f & 7, j = f >> 3;
    int bkv = xcd + 8 * (j & 3);
    int b = bkv >> 3, kv = bkv & 7;
    int rem = j >> 2;
    int h = kv * 2 + (rem & 1);
    int qpair = rem >> 1;

    const unsigned short* qbase = qb + (long)(b * NH + h) * SEQ * HDIM;
    const unsigned short* kbase = kb + (long)(b * NKVH + kv) * SEQ * HDIM;
    const unsigned short* vbase = vtb + (long)(b * NKVH + kv) * HDIM * SEQ;
    const float SCL2 = 0.088388347648318447f * LOG2E;   // scale * log2(e), folded

    const int srow = tid >> 4;                 // staging: row within 16-row group
    const int sswz = (tid & 15) ^ srow;        // staging: swizzled source unit

    for (int phase = 0; phase < 2; phase++) {
        const int qt = (phase == 0) ? qpair : 15 - qpair;
        const int q0 = qt * 128 + w * 32;

        // Q fragments (B-operand layout: lane=q, k-contiguous)
        bf16x8 qf[2][4];
        for (int nt = 0; nt < 2; nt++)
            for (int ks = 0; ks < 4; ks++)
                qf[nt][ks] = *(const bf16x8*)&qbase[(long)(q0 + nt * 16 + ln) * HDIM + ks * 32 + qq * 8];

        float m[2] = { -3e38f, -3e38f }, l[2] = { 0.f, 0.f };
        f32x4 oacc[8][2] = {};

        #pragma unroll 1
        for (int kt = 0; kt <= qt; kt++) {
            const int k0 = kt * 128;

            __syncthreads();   // B_pre: full drain; everyone done with previous K/V/P
            // stage K [key][hd-unit^swz] then V^T [hd][key-unit^swz] (FIFO order)
            char* kl = (char*)KV;
            #pragma unroll
            for (int r = 0; r < 8; r++) {
                int key = r * 16 + srow;
                stage16(kbase + (long)(k0 + key) * HDIM + sswz * 8, kl + r * 4096 + tid * 16);
            }
            #pragma unroll
            for (int r = 0; r < 8; r++) {
                int hd = r * 16 + srow;
                stage16(vbase + (long)hd * SEQ + k0 + sswz * 8, kl + 32768 + r * 4096 + tid * 16);
            }
            // K resident (8 newest = V loads may stay in flight)
            asm volatile("s_waitcnt vmcnt(8)" ::: "memory");
            asm volatile("s_barrier" ::: "memory");

            // ---- S^T = K Q^T : A-frags from swizzled LDS (V still in flight) ----
            f32x4 sacc[8][2] = {};
            #pragma unroll
            for (int mt = 0; mt < 8; mt++) {
                const unsigned short* kr = &KV[(mt * 16 + ln) * 128];
                bf16x8 kf0 = *(const bf16x8*)&kr[((0 + qq) ^ ln) * 8];
                bf16x8 kf1 = *(const bf16x8*)&kr[((4 + qq) ^ ln) * 8];
                bf16x8 kf2 = *(const bf16x8*)&kr[((8 + qq) ^ ln) * 8];
                bf16x8 kf3 = *(const bf16x8*)&kr[((12 + qq) ^ ln) * 8];
                sacc[mt][0] = MFMA(kf0, qf[0][0], sacc[mt][0]);
                sacc[mt][1] = MFMA(kf0, qf[1][0], sacc[mt][1]);
                sacc[mt][0] = MFMA(kf1, qf[0][1], sacc[mt][0]);
                sacc[mt][1] = MFMA(kf1, qf[1][1], sacc[mt][1]);
                sacc[mt][0] = MFMA(kf2, qf[0][2], sacc[mt][0]);
                sacc[mt][1] = MFMA(kf2, qf[1][2], sacc[mt][1]);
                sacc[mt][0] = MFMA(kf3, qf[0][3], sacc[mt][0]);
                sacc[mt][1] = MFMA(kf3, qf[1][3], sacc[mt][1]);
            }

            // B_k: all waves' K ds_reads done -> P overlay safe (no V drain!)
            asm volatile("s_waitcnt lgkmcnt(0)" ::: "memory");
            asm volatile("s_barrier" ::: "memory");

            // ---- online softmax in raw units (scale folded into SCL2) ----
            const bool diag = (kt == qt);
            #pragma unroll
            for (int nt = 0; nt < 2; nt++) {
                const int q = q0 + nt * 16 + ln;
                float mx = -3e38f;
                #pragma unroll
                for (int mt = 0; mt < 8; mt++)
                    #pragma unroll
                    for (int r = 0; r < 4; r++) {
                        float v = sacc[mt][nt][r];
                        if (diag && (k0 + mt * 16 + qq * 4 + r > q)) v = -3e38f;
                        sacc[mt][nt][r] = v;
                        mx = fmaxf(mx, v);
                    }
                mx = fmaxf(mx, __shfl_xor(mx, 16));
                mx = fmaxf(mx, __shfl_xor(mx, 32));
                // defer-max: rescale only when tile max exceeds threshold
                if (!__all(mx <= m[nt] + 62.7f)) {
                    float newm = fmaxf(m[nt], mx);
                    float alpha = exp2f((m[nt] - newm) * SCL2);
                    l[nt] *= alpha;
                    #pragma unroll
                    for (int mt = 0; mt < 8; mt++)
                        #pragma unroll
                        for (int r = 0; r < 4; r++)
                            oacc[mt][nt][r] *= alpha;
                    m[nt] = newm;
                }
                float rs = 0.f;
                #pragma unroll
                for (int mt = 0; mt < 8; mt++) {
                    float p0 = exp2f((sacc[mt][nt][0] - m[nt]) * SCL2);
                    float p1 = exp2f((sacc[mt][nt][1] - m[nt]) * SCL2);
                    float p2 = exp2f((sacc[mt][nt][2] - m[nt]) * SCL2);
                    float p3 = exp2f((sacc[mt][nt][3] - m[nt]) * SCL2);
                    rs += (p0 + p1) + (p2 + p3);
                    us4 pu = { f2bf(p0), f2bf(p1), f2bf(p2), f2bf(p3) };
                    // P[q][key]: row q=nt*16+ln, key-unit mt*2+(qq>>1), swizzle ^ln
                    *(us4*)&Pseg[(nt * 16 + ln) * 128 + ((mt * 2 + (qq >> 1)) ^ ln) * 8 + (qq & 1) * 4] = pu;
                }
                rs += __shfl_xor(rs, 16);
                rs += __shfl_xor(rs, 32);
                l[nt] += rs;
            }

            // V resident + all waves past softmax
            asm volatile("s_waitcnt vmcnt(0)" ::: "memory");
            asm volatile("s_barrier" ::: "memory");

            // ---- O^T += V^T P^T : A = V^T frags, B = P frags (both LDS) ----
            bf16x8 pf[4][2];
            #pragma unroll
            for (int ks = 0; ks < 4; ks++)
                #pragma unroll
                for (int nt = 0; nt < 2; nt++)
                    pf[ks][nt] = *(const bf16x8*)&Pseg[(nt * 16 + ln) * 128 + ((ks * 4 + qq) ^ ln) * 8];
            #pragma unroll
            for (int mt = 0; mt < 8; mt++) {
                const unsigned short* vr = &KV[16384 + (mt * 16 + ln) * 128];
                bf16x8 vf0 = *(const bf16x8*)&vr[((0 + qq) ^ ln) * 8];
                bf16x8 vf1 = *(const bf16x8*)&vr[((4 + qq) ^ ln) * 8];
                bf16x8 vf2 = *(const bf16x8*)&vr[((8 + qq) ^ ln) * 8];
                bf16x8 vf3 = *(const bf16x8*)&vr[((12 + qq) ^ ln) * 8];
                oacc[mt][0] = MFMA(vf0, pf[0][0], oacc[mt][0]);
                oacc[mt][1] = MFMA(vf0, pf[0][1], oacc[mt][1]);
                oacc[mt][0] = MFMA(vf1, pf[1][0], oacc[mt][0]);
                oacc[mt][1] = MFMA(vf1, pf[1][1], oacc[mt][1]);
                oacc[mt][0] = MFMA(vf2, pf[2][0], oacc[mt][0]);
                oacc[mt][1] = MFMA(vf2, pf[2][1], oacc[mt][1]);
                oacc[mt][0] = MFMA(vf3, pf[3][0], oacc[mt][0]);
                oacc[mt][1] = MFMA(vf3, pf[3][1], oacc[mt][1]);
            }
        }

        // ---- epilogue: lane owns column q; d = mt*16 + qq*4 + r ----
        #pragma unroll
        for (int nt = 0; nt < 2; nt++) {
            const int q = q0 + nt * 16 + ln;
            float inv = 1.f / l[nt];
            unsigned short* ao = aout + ((long)b * SEQ + q) * DIM + h * HDIM;
            #pragma unroll
            for (int mt = 0; mt < 8; mt++) {
                us4 o = { f2bf(oacc[mt][nt][0] * inv), f2bf(oacc[mt][nt][1] * inv),
                          f2bf(oacc[mt][nt][2] * inv), f2bf(oacc[mt][nt][3] * inv) };
                *(us4*)&ao[mt * 16 + qq * 4] = o;
            }
        }
    }
}

// ---------------------------------------------------------------------------
// Output GEMM v4 (kept): m201-style 256x256, 4 phases per K-tile, half-tile
// staging, vmcnt(6), setprio.  Grid (8,32) = 1 block/CU.
// ---------------------------------------------------------------------------

// stage one half-tile: operand op (0=A,1=B), half h, K-tile t_, parity p_
#define STAGEH(p_, op_, h_, t_) do {                                              \
    unsigned short* d_ = sh + (p_) * 32768 + (op_) * 16384 + (h_) * 8192 + tid * 8; \
    const unsigned short* s_ = ((op_) ? bg : ag) + (long)((h_) * 128) * K + (t_) * 64; \
    stage16(s_, d_); stage16(s_ + 64 * K, d_ + 4096); } while (0)

#define BARRIER() asm volatile("s_barrier" ::: "memory")
#define WAITLGKM() asm volatile("s_waitcnt lgkmcnt(0)" ::: "memory")

__launch_bounds__(512, 2)
__global__ void out_gemm(const unsigned short* __restrict__ ab,
                         const unsigned short* __restrict__ wt,
                         float* __restrict__ out) {
    constexpr int K  = DIM;
    constexpr int NT = K / 64;
    __shared__ __align__(16) unsigned short sh[65536];
    const int tid = threadIdx.x;
    const int m0 = blockIdx.y * 256;
    const int n0 = blockIdx.x * 256;
    const int w = tid >> 6, lane = tid & 63, qq = lane >> 4, ln = lane & 15;
    const int wm = w >> 2, wn = w & 3;

    f32x4 acc[8][4] = {};

    const int rowq = tid >> 3;
    const int cswz = ((tid & 7) ^ (rowq & 7)) * 8;
    const unsigned short* ag = ab + (long)(m0 + rowq) * K + cswz;
    const unsigned short* bg = wt + (long)(n0 + rowq) * K + cswz;

    const int aoff = wm * 8192 + ln * 64;
    const int boff = 16384 + (wn >> 1) * 8192 + ((wn & 1) * 64 + ln) * 64;
    const int swz0 = ((0 + qq) ^ (ln & 7)) * 8;
    const int swz1 = ((4 + qq) ^ (ln & 7)) * 8;

    STAGEH(0, 1, 0, 0); STAGEH(0, 1, 1, 0); STAGEH(0, 0, 0, 0); STAGEH(0, 0, 1, 0);
    STAGEH(1, 1, 0, 1); STAGEH(1, 0, 0, 1); STAGEH(1, 0, 1, 1);

    #pragma unroll 1
    for (int t = 0; t < NT; t++) {
        const int p = t & 1, pn = p ^ 1;
        if (t >= NT - 1) asm volatile("s_waitcnt vmcnt(0)" ::: "memory");
        else             asm volatile("s_waitcnt vmcnt(6)" ::: "memory");
        BARRIER();

        const unsigned short* Ab = sh + p * 32768;
        bf16x8 af[8][2], bf_[4][2];

        // ---- phase 1
        #pragma unroll
        for (int fc = 0; fc < 4; fc++) {
            bf_[fc][0] = *(const bf16x8*)&Ab[boff + fc * 1024 + swz0];
            bf_[fc][1] = *(const bf16x8*)&Ab[boff + fc * 1024 + swz1];
        }
        #pragma unroll
        for (int fr = 0; fr < 4; fr++) {
            af[fr][0] = *(const bf16x8*)&Ab[aoff + fr * 1024 + swz0];
            af[fr][1] = *(const bf16x8*)&Ab[aoff + fr * 1024 + swz1];
        }
        if (t + 1 < NT) STAGEH(pn, 1, 1, t + 1);
        BARRIER();
        WAITLGKM();
        __builtin_amdgcn_s_setprio(1);
        #pragma unroll
        for (int fr = 0; fr < 4; fr++)
            #pragma unroll
            for (int fc = 0; fc < 2; fc++) {
                acc[fr][fc] = MFMA(af[fr][0], bf_[fc][0], acc[fr][fc]);   // normal C
                acc[fr][fc] = MFMA(af[fr][1], bf_[fc][1], acc[fr][fc]);
            }
        __builtin_amdgcn_s_setprio(0);
        BARRIER();

        // ---- phase 2
        #pragma unroll
        for (int fr = 4; fr < 8; fr++) {
            af[fr][0] = *(const bf16x8*)&Ab[aoff + fr * 1024 + swz0];
            af[fr][1] = *(const bf16x8*)&Ab[aoff + fr * 1024 + swz1];
        }
        if (t + 2 < NT) STAGEH(p, 1, 0, t + 2);
        BARRIER();
        WAITLGKM();
        __builtin_amdgcn_s_setprio(1);
        #pragma unroll
        for (int fr = 0; fr < 4; fr++)
            #pragma unroll
            for (int fc = 2; fc < 4; fc++) {
                acc[fr][fc] = MFMA(af[fr][0], bf_[fc][0], acc[fr][fc]);
                acc[fr][fc] = MFMA(af[fr][1], bf_[fc][1], acc[fr][fc]);
            }
        __builtin_amdgcn_s_setprio(0);
        BARRIER();

        // ---- phase 3
        if (t + 2 < NT) STAGEH(p, 0, 0, t + 2);
        BARRIER();
        __builtin_amdgcn_s_setprio(1);
        #pragma unroll
        for (int fr = 4; fr < 8; fr++)
            #pragma unroll
            for (int fc = 0; fc < 2; fc++) {
                acc[fr][fc] = MFMA(af[fr][0], bf_[fc][0], acc[fr][fc]);
                acc[fr][fc] = MFMA(af[fr][1], bf_[fc][1], acc[fr][fc]);
            }
        __builtin_amdgcn_s_setprio(0);
        BARRIER();

        // ---- phase 4
        if (t + 2 < NT) STAGEH(p, 0, 1, t + 2);
        BARRIER();
        __builtin_amdgcn_s_setprio(1);
        #pragma unroll
        for (int fr = 4; fr < 8; fr++)
            #pragma unroll
            for (int fc = 2; fc < 4; fc++) {
                acc[fr][fc] = MFMA(af[fr][0], bf_[fc][0], acc[fr][fc]);
                acc[fr][fc] = MFMA(af[fr][1], bf_[fc][1], acc[fr][fc]);
            }
        __builtin_amdgcn_s_setprio(0);
        BARRIER();
    }

    // epilogue (normal): m = m0 + wm*128 + fr*16 + qq*4 + r, n = n0 + wn*64 + fc*16 + ln
    for (int fr = 0; fr < 8; fr++)
        for (int fc = 0; fc < 4; fc++) {
            int n = n0 + wn * 64 + fc * 16 + ln;
            for (int r = 0; r < 4; r++) {
                int m = m0 + wm * 128 + fr * 16 + qq * 4 + r;
                out[(long)m * DIM + n] = acc[fr][fc][r];
            }
        }
}

// ---------------------------------------------------------------------------
// Workspace layout: unchanged, total 176,160,768 bytes
// ---------------------------------------------------------------------------
extern "C" void kernel_launch(void* const* d_in, const int* in_sizes, int n_in,
                              void* d_out, int out_size, void* d_ws, size_t ws_size,
                              hipStream_t stream) {
    const float* x    = (const float*)d_in[0];
    const float* wq   = (const float*)d_in[1];
    const float* wk   = (const float*)d_in[2];
    const float* wv   = (const float*)d_in[3];
    const float* wo   = (const float*)d_in[4];
    const float* pcos = (const float*)d_in[5];
    const float* psin = (const float*)d_in[6];
    float* out = (float*)d_out;

    char* ws = (char*)d_ws;
    unsigned short* xb    = (unsigned short*)(ws);
    unsigned short* wqkvt = (unsigned short*)(ws + 33554432L);
    unsigned short* wot   = (unsigned short*)(ws + 50331648L);
    unsigned short* qbuf  = (unsigned short*)(ws + 58720256L);
    unsigned short* kbuf  = (unsigned short*)(ws + 92274688L);
    unsigned short* vbuf  = (unsigned short*)(ws + 109051904L);
    unsigned short* vtb   = (unsigned short*)(ws + 125829120L);
    unsigned short* aout  = (unsigned short*)(ws + 142606336L);

    conv_x<<<16384, 256, 0, stream>>>(x, xb);
    transpose_w<<<dim3(64, 64), dim3(32, 8), 0, stream>>>(wq, wqkvt, 2048, 0);
    transpose_w<<<dim3(32, 64), dim3(32, 8), 0, stream>>>(wk, wqkvt, 1024, 2048);
    transpose_w<<<dim3(32, 64), dim3(32, 8), 0, stream>>>(wv, wqkvt, 1024, 3072);
    transpose_w<<<dim3(64, 64), dim3(32, 8), 0, stream>>>(wo, wot, 2048, 0);

    qkv_gemm<<<dim3(32, 64), 256, 0, stream>>>(xb, wqkvt, pcos, psin, qbuf, kbuf, vbuf);
    transpose_v<<<dim3(4, 64, 32), dim3(32, 8), 0, stream>>>(vbuf, vtb);
    flash<<<dim3(8, 16, 4), 256, 0, stream>>>(qbuf, kbuf, vtb, aout);
    out_gemm<<<dim3(8, 32), 512, 0, stream>>>(aout, wot, out);
}